// Round 15
// baseline (1409.259 us; speedup 1.0000x reference)
//
#include <hip/hip_runtime.h>
#include <cstdint>
#include <cstddef>

#define TPB 256

typedef _Float16 f16x8 __attribute__((ext_vector_type(8)));
typedef float f32x4 __attribute__((ext_vector_type(4)));
typedef const __attribute__((address_space(1))) void* gp1_t;
typedef __attribute__((address_space(3))) void* lp3_t;

// raw barrier: LDS-visibility fence WITHOUT the vmcnt(0) drain __syncthreads emits.
__device__ __forceinline__ void block_sync_lds() {
    asm volatile("s_waitcnt lgkmcnt(0)" ::: "memory");
    __builtin_amdgcn_sched_barrier(0);
    __builtin_amdgcn_s_barrier();
    __builtin_amdgcn_sched_barrier(0);
}

template <int N>
__device__ __forceinline__ void vm_wait() {
    asm volatile("s_waitcnt vmcnt(%0)" :: "i"(N) : "memory");
    __builtin_amdgcn_sched_barrier(0);
}

// ---------------- index-building kernels ----------------

static __global__ void kscatter(int* __restrict__ grid, const int* __restrict__ coords,
                                int N, int S) {
    int i = blockIdx.x * blockDim.x + threadIdx.x;
    if (i >= N) return;
    int x = coords[3 * i], y = coords[3 * i + 1], z = coords[3 * i + 2];
    grid[(x * S + y) * S + z] = i;
}

// invalid neighbors are remapped to zr (the zero-row index)
static __global__ void knbr27(int* __restrict__ nbr, const int* __restrict__ coords,
                              const int* __restrict__ grid, int N, int S, int zr) {
    int t = blockIdx.x * blockDim.x + threadIdx.x;
    if (t >= N * 27) return;
    int n = t / 27, k = t - 27 * n;
    int x = coords[3 * n]     + (k / 9) - 1;
    int y = coords[3 * n + 1] + ((k / 3) % 3) - 1;
    int z = coords[3 * n + 2] + (k % 3) - 1;
    int v = -1;
    if ((unsigned)x < (unsigned)S && (unsigned)y < (unsigned)S && (unsigned)z < (unsigned)S)
        v = grid[(x * S + y) * S + z];
    nbr[t] = (v < 0) ? zr : v;
}

static __global__ void kdown8(int* __restrict__ dn, const int* __restrict__ coords,
                              const int* __restrict__ grid, int M, int S_f, int zr) {
    int t = blockIdx.x * blockDim.x + threadIdx.x;
    if (t >= M * 8) return;
    int n = t >> 3, k = t & 7;
    int x = coords[3 * n] * 2     + ((k >> 2) & 1);
    int y = coords[3 * n + 1] * 2 + ((k >> 1) & 1);
    int z = coords[3 * n + 2] * 2 + (k & 1);
    int v = grid[(x * S_f + y) * S_f + z];
    dn[t] = (v < 0) ? zr : v;
}

static __global__ void kup(int* __restrict__ up, const int* __restrict__ cf,
                           const int* __restrict__ gc, int N, int Sc) {
    int n = blockIdx.x * blockDim.x + threadIdx.x;
    if (n >= N) return;
    int x = cf[3 * n] >> 2, y = cf[3 * n + 1] >> 2, z = cf[3 * n + 2] >> 2;
    up[n] = gc[(x * Sc + y) * Sc + z];       // parent always exists
}

// Pre-permuted split weights for global_load_lds staging (rule #21: linear LDS
// dest + inverse-swizzled SOURCE). For each iteration it, the WSBH-half block
// holds the W tile in PHYSICAL LDS order: chunk s = (row, pq) stores logical
// chunk q = pq ^ (row & (PKT-1)). Pad taps/chunks/elems are zero.
static __global__ void ksplitw_perm(_Float16* __restrict__ dst, const float* __restrict__ src,
                                    int TAPS, int TPI, int QQ, int KTCH, int PKT,
                                    int A, int B, int WSBH, long total) {
    long t = (long)blockIdx.x * blockDim.x + threadIdx.x;
    if (t >= total) return;
    int it = (int)(t / WSBH);
    int r = (int)(t - (long)it * WSBH);
    int s = r >> 3, j = r & 7;
    int row = s / PKT, pq = s - row * PKT;
    int q = pq ^ (row & (PKT - 1));
    float v = 0.0f;
    if (q < KTCH) {
        int tq = q / QQ, qq = q - tq * QQ;
        int k = it * TPI + tq;
        int a = qq * 8 + j;
        if (k < TAPS && a < A)
            v = src[((size_t)k * A + a) * B + (row % B)];
    }
    _Float16 hi = (_Float16)v;
    dst[t] = (row >= B) ? (_Float16)(v - (float)hi) : hi;
}

// ---------------- BN stats + fused BN-ReLU-split pass ----------------
// stats slot layout: 16 copies x 160 doubles. kstats writes copy 0; fused conv
// epilogues spread over all 16; kbnrelu sums the 16 copies.
// FEATURE row layout: interleaved granules [hi0 lo0 hi1 lo1 ...] -- each
// (hi,lo) fragment pair of chunk cq sits in ONE 64B line.

static __global__ void kstats(double* __restrict__ st, const float* __restrict__ x,
                              int N, int C) {
    extern __shared__ double sh[];          // 2 * 4*C doubles
    int tid = threadIdx.x;
    int c = tid % C, rl = tid / C;
    double s = 0.0, q = 0.0;
    int base = blockIdx.x * 256 + rl * 64;
    for (int it = 0; it < 64; it++) {
        int r = base + it;
        if (r < N) {
            double v = (double)x[(size_t)r * C + c];
            s += v;
            q = fma(v, v, q);
        }
    }
    double* ss = sh;
    double* sq = sh + 4 * C;
    ss[tid] = s; sq[tid] = q;
    __syncthreads();
    if (tid < C) {
        double S = ss[tid] + ss[tid + C] + ss[tid + 2 * C] + ss[tid + 3 * C];
        double Q = sq[tid] + sq[tid + C] + sq[tid + 2 * C] + sq[tid + 3 * C];
        atomicAdd(&st[tid], S);
        atomicAdd(&st[80 + tid], Q);
    }
}

// y has N+1 rows; row N is the zero row. Interleaved granule layout.
static __global__ void kbnrelu_h(_Float16* __restrict__ y, const float4* __restrict__ x,
                                 const double* __restrict__ st, const float* __restrict__ g,
                                 const float* __restrict__ b, int N, int C) {
    __shared__ float sc[80], bh[80];
    int tid = threadIdx.x;
    if (tid < C) {
        double invN = 1.0 / (double)N;
        double S = 0.0, Q = 0.0;
#pragma unroll
        for (int c = 0; c < 16; c++) {
            S += st[c * 160 + tid];
            Q += st[c * 160 + 80 + tid];
        }
        double mu = S * invN;
        double var = Q * invN - mu * mu;
        float s = g[tid] * rsqrtf((float)var + 1e-4f);
        sc[tid] = s;
        bh[tid] = b[tid] - (float)mu * s;
    }
    __syncthreads();
    int C8 = C >> 3;
    int chunks = (N + 1) * C8;
    int t = blockIdx.x * blockDim.x + tid;
    if (t >= chunks) return;
    int n = t / C8, cc = t - n * C8;
    f16x8 hi = {}, lo = {};
    if (n < N) {
        float4 q0 = x[n * (C >> 2) + cc * 2];
        float4 q1 = x[n * (C >> 2) + cc * 2 + 1];
        float v[8] = {q0.x, q0.y, q0.z, q0.w, q1.x, q1.y, q1.z, q1.w};
#pragma unroll
        for (int j = 0; j < 8; j++) {
            float r = fmaxf(fmaf(v[j], sc[cc * 8 + j], bh[cc * 8 + j]), 0.0f);
            _Float16 h = (_Float16)r;
            hi[j] = h;
            lo[j] = (_Float16)(r - (float)h);
        }
    }
    *(f16x8*)&y[(size_t)n * 2 * C + cc * 16] = hi;
    *(f16x8*)&y[(size_t)n * 2 * C + cc * 16 + 8] = lo;
}

// fp32 -> split f16 (for ppn1 input); N+1 rows, last zeroed; interleaved
static __global__ void kcvt_h(_Float16* __restrict__ y, const float4* __restrict__ x,
                              int N, int C) {
    int C8 = C >> 3;
    int t = blockIdx.x * blockDim.x + threadIdx.x;
    if (t >= (N + 1) * C8) return;
    int n = t / C8, cc = t - n * C8;
    f16x8 hi = {}, lo = {};
    if (n < N) {
        float4 q0 = x[n * (C >> 2) + cc * 2];
        float4 q1 = x[n * (C >> 2) + cc * 2 + 1];
        float v[8] = {q0.x, q0.y, q0.z, q0.w, q1.x, q1.y, q1.z, q1.w};
#pragma unroll
        for (int j = 0; j < 8; j++) {
            _Float16 h = (_Float16)v[j];
            hi[j] = h;
            lo[j] = (_Float16)(v[j] - (float)h);
        }
    }
    *(f16x8*)&y[(size_t)n * 2 * C + cc * 16] = hi;
    *(f16x8*)&y[(size_t)n * 2 * C + cc * 16 + 8] = lo;
}

// attention multiply + split; N+1 rows, last zeroed; interleaved
static __global__ void kmulatt_h(_Float16* __restrict__ y, const float4* __restrict__ fmap,
                                 const int* __restrict__ up, const float* __restrict__ sc,
                                 int N, int C) {
    int C8 = C >> 3;
    int t = blockIdx.x * blockDim.x + threadIdx.x;
    if (t >= (N + 1) * C8) return;
    int n = t / C8, cc = t - n * C8;
    f16x8 hi = {}, lo = {};
    if (n < N) {
        int p = up[n];
        float att = (sc[2 * p + 1] > sc[2 * p]) ? 1.0f : 0.0f;
        float4 q0 = fmap[n * (C >> 2) + cc * 2];
        float4 q1 = fmap[n * (C >> 2) + cc * 2 + 1];
        float v[8] = {q0.x, q0.y, q0.z, q0.w, q1.x, q1.y, q1.z, q1.w};
#pragma unroll
        for (int j = 0; j < 8; j++) {
            float r = v[j] * att;
            _Float16 h = (_Float16)r;
            hi[j] = h;
            lo[j] = (_Float16)(r - (float)h);
        }
    }
    *(f16x8*)&y[(size_t)n * 2 * C + cc * 16] = hi;
    *(f16x8*)&y[(size_t)n * 2 * C + cc * 16 + 8] = lo;
}

// ---------------- split-f16 MFMA sparse conv: deep-K iterations ---------------
// out[n,b] (+= res) = sum_k sum_a feat[nbr[n,k],a] * W[k,a,b], computed as
// hi*hi + lo*hi + hi*lo with mfma_f32_16x16x32_f16 (fp32 acc).
// r13 structure (single-set A regs after MFMA; pre-permuted gload_lds W, zero
// conflicts) with DEEP TPI: 2-4x more K per iteration stretches the compute
// phase (~1100cy at 48ch) over the SAME ~900cy gather latency -> stall
// fraction halves, and barrier count halves (14->7 iters at 48ch). down0
// becomes a single-iteration kernel. PKT extended to 32 (KTCH=24 pad).
// Tap-select in loadA is a static ternary chain (rule #20-safe for any TPI).

template <int A, int B, int TAPS, int TPI, int NW, int MT, int KG, bool ADD>
__launch_bounds__(NW * 64, 2)
static __global__ void kconvmf(float* __restrict__ out, const _Float16* __restrict__ feat,
                               const int* __restrict__ nbr, const _Float16* __restrict__ Wsp,
                               const float* __restrict__ res, double* __restrict__ stp,
                               int N, int zr) {
    constexpr int TR = NW * MT * 16;
    constexpr int NT_W = B / 16;                    // all waves cover all cols
    constexpr int KPT = (TPI == 1) ? ((A + 31) & ~31)
                      : (TPI == 2) ? ((A + 15) & ~15)
                                   : ((A + 7) & ~7);
    constexpr int KT = TPI * KPT;
    static_assert(KT % 32 == 0, "KT must be multiple of 32");
    constexpr int KSTEPS = KT / 32;
    constexpr int KTCH = KT / 8;                    // logical 16B chunks per row
    constexpr int PKT = (KTCH <= 8) ? 8 : (KTCH <= 16) ? 16 : 32;
    static_assert(KTCH <= PKT && (PKT & (PKT - 1)) == 0, "bad PKT");
    constexpr int RH = PKT * 8;                     // halves per weight row
    constexpr int QQ = KPT / 8;
    constexpr int AQ = A / 8;
    constexpr int A2 = 2 * A;
    constexpr int ITERS = (TAPS + TPI - 1) / TPI;
    constexpr int IPG = (ITERS + KG - 1) / KG;
    constexpr int WROWS = 2 * B;
    constexpr int WSBH = WROWS * RH;                // halves in W buffer
    constexpr int SEGW = WSBH / 512;                // 1KB gload_lds segments
    static_assert(SEGW * 512 == WSBH, "W tile must split into 1KB segments");
    constexpr int ASEG = MT * KSTEPS * 2;           // A global loads per iter

    __shared__ __attribute__((aligned(16))) _Float16 wsb[WSBH];
    __shared__ double sred[(KG == 1) ? NW * 2 * B : 1];

    const int tid = threadIdx.x;

    // bijective XCD swizzle (m204)
    int bx;
    {
        int nwg = gridDim.x, bid = blockIdx.x;
        int q = nwg >> 3, r = nwg & 7, xcd = bid & 7, ix = bid >> 3;
        bx = (xcd < r) ? xcd * (q + 1) + ix : r * (q + 1) + (xcd - r) * q + ix;
    }
    const int row0 = bx * TR;
    const int it0 = (KG > 1) ? blockIdx.y * IPG : 0;
    const int it1 = (KG > 1) ? ((it0 + IPG < ITERS) ? it0 + IPG : ITERS) : ITERS;

    const int lane = tid & 63, wid = tid >> 6;
    const int lrow = lane & 15, lgrp = lane >> 4;
    const int mb = wid * MT * 16;

    int rowm[MT];
#pragma unroll
    for (int mt = 0; mt < MT; mt++) rowm[mt] = row0 + mb + mt * 16 + lrow;

    f32x4 acc[MT][NT_W];
#pragma unroll
    for (int mt = 0; mt < MT; mt++)
#pragma unroll
        for (int nt = 0; nt < NT_W; nt++)
            acc[mt][nt] = (f32x4){0.f, 0.f, 0.f, 0.f};

    int nidA[MT][TPI], nidB[MT][TPI];
    f16x8 fa[MT][KSTEPS][2];                 // single-set A fragments

    auto loadnbr = [&](auto& nd, int it) {
        int tb = it * TPI;
#pragma unroll
        for (int mt = 0; mt < MT; mt++)
#pragma unroll
            for (int t = 0; t < TPI; t++)
                nd[mt][t] = (rowm[mt] < N && tb + t < TAPS)
                          ? nbr[(size_t)rowm[mt] * TAPS + tb + t] : zr;
    };
    // interleaved feature rows: granule pair (hi,lo) of chunk cq at halves
    // [cq*16, cq*16+16) -- one 64B line per pair.
    auto loadA = [&](const auto& nd) {
#pragma unroll
        for (int mt = 0; mt < MT; mt++)
#pragma unroll
            for (int ks = 0; ks < KSTEPS; ks++) {
                int qc = ks * 4 + lgrp;
                int t = qc / QQ;
                int cq = qc - t * QQ;
                int id = nd[mt][0];              // static ternary select chain
#pragma unroll
                for (int tt = 1; tt < TPI; tt++) id = (t == tt) ? nd[mt][tt] : id;
                const _Float16* p = feat + (size_t)id * A2 + cq * 16;
                if constexpr (QQ > AQ) {
                    bool okc = (cq < AQ);
                    fa[mt][ks][0] = okc ? *(const f16x8*)p : (f16x8){};
                    fa[mt][ks][1] = okc ? *(const f16x8*)(p + 8) : (f16x8){};
                } else {
                    fa[mt][ks][0] = *(const f16x8*)p;
                    fa[mt][ks][1] = *(const f16x8*)(p + 8);
                }
            }
    };
    // fire-and-forget W staging: wave-strided 1KB linear segments
    auto issueW = [&](int it) {
        const _Float16* base = Wsp + (size_t)it * WSBH;
#pragma unroll
        for (int i = 0; i < (SEGW + NW - 1) / NW; i++) {
            int s = wid + i * NW;
            if (SEGW % NW == 0 || s < SEGW)
                __builtin_amdgcn_global_load_lds((gp1_t)(base + s * 512 + lane * 8),
                                                 (lp3_t)(wsb + s * 512), 16, 0, 0);
        }
    };
    auto domfma = [&]() {
#pragma unroll
        for (int ks = 0; ks < KSTEPS; ++ks) {
            const int qc = ks * 4 + lgrp;
            f16x8 bh[NT_W], bl[NT_W];
#pragma unroll
            for (int nt = 0; nt < NT_W; ++nt) {
                int rH = nt * 16 + lrow;
                bh[nt] = *(const f16x8*)&wsb[rH * RH + (qc ^ (rH & (PKT - 1))) * 8];
                int rL = B + rH;
                bl[nt] = *(const f16x8*)&wsb[rL * RH + (qc ^ (rL & (PKT - 1))) * 8];
            }
#pragma unroll
            for (int mt = 0; mt < MT; ++mt)
#pragma unroll
                for (int nt = 0; nt < NT_W; ++nt) {
                    acc[mt][nt] = __builtin_amdgcn_mfma_f32_16x16x32_f16(fa[mt][ks][0], bh[nt], acc[mt][nt], 0, 0, 0);
                    acc[mt][nt] = __builtin_amdgcn_mfma_f32_16x16x32_f16(fa[mt][ks][1], bh[nt], acc[mt][nt], 0, 0, 0);
                    acc[mt][nt] = __builtin_amdgcn_mfma_f32_16x16x32_f16(fa[mt][ks][0], bl[nt], acc[mt][nt], 0, 0, 0);
                }
        }
    };

    // prologue: W(it0)+A(it0) staged; nbr(it0+1) prefetched; single full drain
    loadnbr(nidA, it0);
    issueW(it0);
    __builtin_amdgcn_sched_barrier(0);
    loadA(nidA);
    if (it0 + 1 < it1) loadnbr(nidB, it0 + 1);
    vm_wait<0>();
    block_sync_lds();                    // W(it0) visible to all waves

    // body(it): MFMA(it) | barrier (W(it) reads done) | issueW(it+1) |
    //   sched_barrier | loadA(it+1) (regs freed by MFMA) | nbr(it+2) |
    //   vmcnt(ASEG): own W(it+1) drained (oldest), A+nbr in flight | barrier.
    auto body = [&](auto& ncur, const auto& nnx, int it) {
        const bool m1 = (it + 1 < it1), m2 = (it + 2 < it1);
        domfma();
        if (m1) {
            block_sync_lds();            // all waves done reading wsb (W(it))
            issueW(it + 1);
            __builtin_amdgcn_sched_barrier(0);
            loadA(nnx);                  // A(it+1); auto-waited by next domfma
            if (m2) loadnbr(ncur, it + 2);
            vm_wait<ASEG>();             // drains own W(it+1); A stays in flight
            block_sync_lds();            // W(it+1) visible
        }
    };
    for (int it = it0; it < it1; ) {
        body(nidA, nidB, it); ++it;
        if (it >= it1) break;
        body(nidB, nidA, it); ++it;
    }

    // epilogue: C layout col=lane&15, row=(lane>>4)*4+j; optional fused BN stats
    const bool dostats = (stp != nullptr);
    double ssum[NT_W], sqs[NT_W];
#pragma unroll
    for (int nt = 0; nt < NT_W; nt++) { ssum[nt] = 0.0; sqs[nt] = 0.0; }
#pragma unroll
    for (int mt = 0; mt < MT; ++mt) {
        int gr0 = row0 + mb + mt * 16 + lgrp * 4;
#pragma unroll
        for (int nt = 0; nt < NT_W; ++nt) {
            int gc = nt * 16 + lrow;
#pragma unroll
            for (int j = 0; j < 4; ++j) {
                int r = gr0 + j;
                if (r < N) {
                    size_t o = (size_t)r * B + gc;
                    if (KG > 1) {
                        atomicAdd(&out[o], acc[mt][nt][j]);
                    } else {
                        float v = acc[mt][nt][j];
                        if (ADD) v += res[o];
                        out[o] = v;
                        if (dostats) {
                            double dv = (double)v;
                            ssum[nt] += dv;
                            sqs[nt] = fma(dv, dv, sqs[nt]);
                        }
                    }
                }
            }
        }
    }
    if (KG == 1) {
        if (dostats) {
#pragma unroll
            for (int nt = 0; nt < NT_W; nt++) {
                ssum[nt] += __shfl_xor(ssum[nt], 16, 64);
                ssum[nt] += __shfl_xor(ssum[nt], 32, 64);
                sqs[nt] += __shfl_xor(sqs[nt], 16, 64);
                sqs[nt] += __shfl_xor(sqs[nt], 32, 64);
            }
            if (lgrp == 0) {
#pragma unroll
                for (int nt = 0; nt < NT_W; nt++) {
                    sred[(wid * 2 + 0) * B + nt * 16 + lrow] = ssum[nt];
                    sred[(wid * 2 + 1) * B + nt * 16 + lrow] = sqs[nt];
                }
            }
            __syncthreads();
            if (wid == 0) {
                double* sb = stp + (bx & 15) * 160;
                for (int c = lane; c < B; c += 64) {
                    double S = 0.0, Q = 0.0;
#pragma unroll
                    for (int w = 0; w < NW; w++) {
                        S += sred[(2 * w) * B + c];
                        Q += sred[(2 * w + 1) * B + c];
                    }
                    atomicAdd(&sb[c], S);
                    atomicAdd(&sb[80 + c], Q);
                }
            }
        }
    }
}

// input layer: A=1, B=16; vectorized over b-quads; fp32 (tiny)
static __global__ void kconv_in(float* __restrict__ out, const float* __restrict__ f,
                                const int* __restrict__ nbr, const float* __restrict__ W,
                                int N, int zr) {
    int t = blockIdx.x * blockDim.x + threadIdx.x;
    if (t >= N * 4) return;
    int n = t >> 2, bq = t & 3;
    float4 acc = make_float4(0.f, 0.f, 0.f, 0.f);
    const float4* W4 = (const float4*)W;
    for (int k = 0; k < 27; k++) {
        int id = nbr[n * 27 + k];
        if (id == zr) continue;
        float v = f[id];
        float4 w = W4[k * 4 + bq];
        acc.x = fmaf(v, w.x, acc.x);
        acc.y = fmaf(v, w.y, acc.y);
        acc.z = fmaf(v, w.z, acc.z);
        acc.w = fmaf(v, w.w, acc.w);
    }
    ((float4*)out)[n * 4 + bq] = acc;
}

// ---------------- heads / epilogue ----------------

static __global__ void kscores(float* __restrict__ sc, const float* __restrict__ x,
                               const float* __restrict__ w, int N, int C) {
    int n = blockIdx.x * blockDim.x + threadIdx.x;
    if (n >= N) return;
    float s0 = 0.0f, s1 = 0.0f;
    const float* xr = x + (size_t)n * C;
    for (int c = 0; c < C; c++) {
        float v = xr[c];
        s0 = fmaf(v, w[2 * c], s0);
        s1 = fmaf(v, w[2 * c + 1], s1);
    }
    sc[2 * n] = s0;
    sc[2 * n + 1] = s1;
}

static __global__ void kout0(float* __restrict__ out, const float* __restrict__ z,
                             const float* __restrict__ pw, const float* __restrict__ sw,
                             int N) {
    int n = blockIdx.x * blockDim.x + threadIdx.x;
    if (n >= N) return;
    float o0 = 0, o1 = 0, o2 = 0, o3 = 0, o4 = 0;
    const float* zr = z + (size_t)n * 16;
#pragma unroll
    for (int c = 0; c < 16; c++) {
        float v = zr[c];
        o0 = fmaf(v, pw[3 * c], o0);
        o1 = fmaf(v, pw[3 * c + 1], o1);
        o2 = fmaf(v, pw[3 * c + 2], o2);
        o3 = fmaf(v, sw[2 * c], o3);
        o4 = fmaf(v, sw[2 * c + 1], o4);
    }
    float* r = out + (size_t)n * 5;
    r[0] = o0; r[1] = o1; r[2] = o2; r[3] = o3; r[4] = o4;
}

static __global__ void koutc(float* __restrict__ out, const int* __restrict__ coords,
                             const float* __restrict__ sc, int N) {
    int n = blockIdx.x * blockDim.x + threadIdx.x;
    if (n >= N) return;
    float* r = out + (size_t)n * 5;
    r[0] = (float)coords[3 * n];
    r[1] = (float)coords[3 * n + 1];
    r[2] = (float)coords[3 * n + 2];
    r[3] = sc[2 * n];
    r[4] = sc[2 * n + 1];
}

// ---------------- host-side helpers ----------------

static inline int cdiv(long a, int b) { return (int)((a + b - 1) / b); }

struct WGeom { int tpi, kpt, ktch, pkt, wsbh, iters; size_t halves; };
static WGeom wgeom(int A, int B, int TAPS, int tpi) {
    WGeom g; g.tpi = tpi;
    g.kpt = (tpi == 1) ? ((A + 31) & ~31) : (tpi == 2) ? ((A + 15) & ~15) : ((A + 7) & ~7);
    int kt = tpi * g.kpt;
    g.ktch = kt / 8;
    g.pkt = (g.ktch <= 8) ? 8 : (g.ktch <= 16) ? 16 : 32;
    g.wsbh = 2 * B * g.pkt * 8;
    g.iters = (TAPS + tpi - 1) / tpi;
    g.halves = (size_t)g.wsbh * g.iters;
    return g;
}

static void splitw(hipStream_t s, _Float16* dst, const float* src, int A, int B,
                   int TAPS, const WGeom& g) {
    long total = (long)g.halves;
    ksplitw_perm<<<cdiv(total, TPB), TPB, 0, s>>>(dst, src, TAPS, g.tpi, g.kpt / 8,
                                                  g.ktch, g.pkt, A, B, g.wsbh, total);
}

static void conv(hipStream_t s, float* out, const _Float16* feat, const int* nbr,
                 const _Float16* Wsp, const float* res, double* stp,
                 int N, int A, int B, int TAPS, int zr) {
#define CASE(AA, BB, TT, TPI_, NW_, MT_, KG_)                                              \
    else if (A == AA && B == BB && TAPS == TT) {                                           \
        if (KG_ > 1 && !res) hipMemsetAsync(out, 0, (size_t)N * BB * 4, s);                \
        dim3 g(cdiv(N, NW_ * MT_ * 16), KG_), blk(NW_ * 64);                               \
        if (res) kconvmf<AA, BB, TT, TPI_, NW_, MT_, KG_, true><<<g, blk, 0, s>>>(out, feat, nbr, Wsp, res, stp, N, zr); \
        else     kconvmf<AA, BB, TT, TPI_, NW_, MT_, KG_, false><<<g, blk, 0, s>>>(out, feat, nbr, Wsp, nullptr, stp, N, zr); \
    }
    if (false) {}
    //    A   B  TAPS TPI NW MT KG    W-LDS / iters / blocks
    CASE(16, 16, 27,  8,  4, 1, 1)   //  8KB, 4it, ~1560
    CASE(32, 32, 27,  4,  4, 1, 1)   // 16KB, 7it, ~1460
    CASE(48, 48, 27,  4,  4, 1, 1)   // 48KB, 7it, ~992
    CASE(64, 64, 27,  2,  4, 1, 4)   // 32KB, 14it/4, ~215x4
    CASE(80, 80, 27,  1,  4, 1, 9)   // 40KB, 27it/9, 27x9
    CASE(16, 32,  8,  8,  4, 1, 1)   // 16KB, 1it, ~1460
    CASE(32, 48,  8,  4,  4, 1, 1)   // 24KB, 2it, ~992
    CASE(48, 64,  8,  2,  4, 1, 2)   // 32KB, 4it/2, ~215x2
    CASE(64, 80,  8,  1,  4, 1, 4)   // 20KB, 8it/4, 27x4
#undef CASE
}

static void bnapply(hipStream_t s, _Float16* out, const float* x, double* st,
                    const float* g, const float* b, int N, int C, bool pre) {
    if (!pre)
        kstats<<<cdiv(N, 256), 4 * C, 8 * C * 2 * sizeof(double), s>>>(st, x, N, C);
    int chunks = (N + 1) * (C / 8);
    kbnrelu_h<<<cdiv(chunks, 256), 256, 0, s>>>(out, (const float4*)x, st, g, b, N, C);
}

extern "C" void kernel_launch(void* const* d_in, const int* in_sizes, int n_in,
                              void* d_out, int out_size, void* d_ws, size_t ws_size,
                              hipStream_t stream) {
    (void)n_in; (void)out_size; (void)ws_size;
    const int SL[5] = {192, 96, 48, 24, 12};
    const int C[5] = {16, 32, 48, 64, 80};
    const int TPI_SUB[4] = {8, 4, 4, 2};
    const int TPI_DN[4] = {8, 4, 2, 1};
    int N[5];
    const int* coords[5];
    for (int l = 0; l < 5; l++) { N[l] = in_sizes[l] / 3; coords[l] = (const int*)d_in[l]; }
    const float* features = (const float*)d_in[5];
    const float* w_in = (const float*)d_in[6];
    const float *blk_w[4], *blk_g[4], *blk_b[4], *dn_g[4], *dn_b[4], *dn_w[4];
    for (int i = 0; i < 4; i++) {
        blk_w[i] = (const float*)d_in[7 + 6 * i];
        blk_g[i] = (const float*)d_in[8 + 6 * i];
        blk_b[i] = (const float*)d_in[9 + 6 * i];
        dn_g[i] = (const float*)d_in[10 + 6 * i];
        dn_b[i] = (const float*)d_in[11 + 6 * i];
        dn_w[i] = (const float*)d_in[12 + 6 * i];
    }
    const float* ppn1_w  = (const float*)d_in[31];
    const float* ppn1_sw = (const float*)d_in[32];
    const float* ppn2_w  = (const float*)d_in[33];
    const float* ppn2_sw = (const float*)d_in[34];
    const float* ppn3_w  = (const float*)d_in[35];
    const float* ppn3_pw = (const float*)d_in[36];
    const float* ppn3_sw = (const float*)d_in[37];
    float* dout = (float*)d_out;

    // ---- weight geometries ----
    WGeom gsub[4], gdn[4];
    for (int i = 0; i < 4; i++) {
        gsub[i] = wgeom(C[i], C[i], 27, TPI_SUB[i]);
        gdn[i] = wgeom(C[i], C[i + 1], 8, TPI_DN[i]);
    }
    WGeom gp1 = wgeom(80, 80, 27, 1);
    WGeom gp2 = wgeom(48, 48, 27, 4);
    WGeom gp3 = wgeom(16, 16, 27, 8);

    // ---- workspace layout ----
    char* ws = (char*)d_ws;
    size_t off = 0;
    auto alloc = [&](size_t bytes) -> char* {
        off = (off + 255) & ~(size_t)255;
        char* p = ws + off;
        off += bytes;
        return p;
    };
    int* nbr[5];
    for (int l = 0; l < 5; l++) nbr[l] = (int*)alloc((size_t)N[l] * 27 * 4);
    int* down8[4];
    for (int i = 0; i < 4; i++) down8[i] = (int*)alloc((size_t)N[i + 1] * 8 * 4);
    int* up1 = (int*)alloc((size_t)N[2] * 4);
    int* up2 = (int*)alloc((size_t)N[0] * 4);
    double* stats = (double*)alloc((size_t)26 * 2560 * sizeof(double));
    _Float16* blkWsp[4];
    _Float16* dnWsp[4];
    for (int i = 0; i < 4; i++) {
        blkWsp[i] = (_Float16*)alloc(4 * gsub[i].halves * 2);
        dnWsp[i] = (_Float16*)alloc(gdn[i].halves * 2);
    }
    _Float16* p1Wsp = (_Float16*)alloc(gp1.halves * 2);
    _Float16* p2Wsp = (_Float16*)alloc(gp2.halves * 2);
    _Float16* p3Wsp = (_Float16*)alloc(gp3.halves * 2);
    float* fmap0 = (float*)alloc((size_t)N[0] * 16 * 4);
    float* fmap2 = (float*)alloc((size_t)N[2] * 48 * 4);
    float* sc1 = (float*)alloc((size_t)N[4] * 2 * 4);
    float* sc2 = (float*)alloc((size_t)N[2] * 2 * 4);

    // transient region: grids (phase 1) alias the 3 rotating feature buffers (phase 2)
    size_t BIG = 0;
    for (int l = 0; l < 5; l++) {
        size_t s = (size_t)(N[l] + 1) * C[l] * 4;   // split rows = same bytes as fp32
        if (s > BIG) BIG = s;
    }
    BIG = (BIG + 255) & ~(size_t)255;
    off = (off + 255) & ~(size_t)255;
    size_t trans = off;
    int* grid[5];
    size_t gtot = 0;
    for (int l = 0; l < 5; l++) {
        grid[l] = (int*)(ws + trans + gtot);
        gtot += (size_t)SL[l] * SL[l] * SL[l] * 4;
    }
    float* B0 = (float*)(ws + trans);
    float* B1 = (float*)(ws + trans + BIG);
    float* B2 = (float*)(ws + trans + 2 * BIG);

    // ---- phase 1: index structures + weight permute-splits + stats zero ----
    hipMemsetAsync(ws + trans, 0xFF, gtot, stream);  // all grids = -1
    hipMemsetAsync(stats, 0, (size_t)26 * 2560 * sizeof(double), stream);
    for (int l = 0; l < 5; l++)
        kscatter<<<cdiv(N[l], TPB), TPB, 0, stream>>>(grid[l], coords[l], N[l], SL[l]);
    for (int l = 0; l < 5; l++)
        knbr27<<<cdiv((long)N[l] * 27, TPB), TPB, 0, stream>>>(nbr[l], coords[l], grid[l], N[l], SL[l], N[l]);
    for (int i = 0; i < 4; i++)
        kdown8<<<cdiv((long)N[i + 1] * 8, TPB), TPB, 0, stream>>>(down8[i], coords[i + 1], grid[i], N[i + 1], SL[i], N[i]);
    kup<<<cdiv(N[2], TPB), TPB, 0, stream>>>(up1, coords[2], grid[4], N[2], 12);
    kup<<<cdiv(N[0], TPB), TPB, 0, stream>>>(up2, coords[0], grid[2], N[0], 48);
    for (int i = 0; i < 4; i++) {
        for (int c = 0; c < 4; c++)
            splitw(stream, blkWsp[i] + (size_t)c * gsub[i].halves,
                   blk_w[i] + (size_t)c * 27 * C[i] * C[i], C[i], C[i], 27, gsub[i]);
        splitw(stream, dnWsp[i], dn_w[i], C[i], C[i + 1], 8, gdn[i]);
    }
    splitw(stream, p1Wsp, ppn1_w, 80, 80, 27, gp1);
    splitw(stream, p2Wsp, ppn2_w, 48, 48, 27, gp2);
    splitw(stream, p3Wsp, ppn3_w, 16, 16, 27, gp3);

    // ---- phase 2: network (grids dead; B0/B1/B2 alias that memory) ----
    int slot = 0;
    auto stn = [&]() { return stats + 2560 * (slot++); };
    auto stpeek = [&]() { return stats + 2560 * slot; };

    float* curX = B0;
    kconv_in<<<cdiv((long)N[0] * 4, TPB), TPB, 0, stream>>>(curX, features, nbr[0], w_in, N[0], N[0]);
    hipMemcpyAsync(fmap0, curX, (size_t)N[0] * 16 * 4, hipMemcpyDeviceToDevice, stream);

    auto others = [&](float* cur, float*& t1, float*& t2) {
        if (cur == B0) { t1 = B1; t2 = B2; }
        else if (cur == B1) { t1 = B0; t2 = B2; }
        else { t1 = B0; t2 = B1; }
    };

    bool entryPre = false;   // stats for current curX already fused by its producer?
    for (int i = 0; i < 4; i++) {
        int Ni = N[i], Ci = C[i];
        float *T1, *T2;
        others(curX, T1, T2);
        bool fuseL = (i < 3);                 // this level's 27-tap convs are KG==1
        for (int r = 0; r < 2; r++) {
            bnapply(stream, (_Float16*)T1, curX, stn(), blk_g[i] + (2 * r) * Ci,
                    blk_b[i] + (2 * r) * Ci, Ni, Ci, r == 0 ? entryPre : fuseL);
            conv(stream, T2, (const _Float16*)T1, nbr[i], blkWsp[i] + (size_t)(2 * r) * gsub[i].halves,
                 nullptr, fuseL ? stpeek() : nullptr, Ni, Ci, Ci, 27, Ni);
            bnapply(stream, (_Float16*)T1, T2, stn(), blk_g[i] + (2 * r + 1) * Ci,
                    blk_b[i] + (2 * r + 1) * Ci, Ni, Ci, fuseL);
            conv(stream, curX, (const _Float16*)T1, nbr[i], blkWsp[i] + (size_t)(2 * r + 1) * gsub[i].halves,
                 curX, fuseL ? stpeek() : nullptr, Ni, Ci, Ci, 27, Ni);
        }
        bnapply(stream, (_Float16*)T1, curX, stn(), dn_g[i], dn_b[i], Ni, Ci, fuseL);
        bool fuseD = (i < 2);                 // down0/down1 are KG==1
        conv(stream, T2, (const _Float16*)T1, down8[i], dnWsp[i], nullptr,
             fuseD ? stpeek() : nullptr, N[i + 1], Ci, C[i + 1], 8, Ni);
        entryPre = fuseD;
        if (i == 1)
            hipMemcpyAsync(fmap2, T2, (size_t)N[2] * 48 * 4, hipMemcpyDeviceToDevice, stream);
        curX = T2;
    }

    // ---- heads ----
    float *T1, *T2;
    others(curX, T1, T2);
    // ppn1 @ level 4: convert level-4 features to split-f16 (with zero row)
    kcvt_h<<<cdiv((N[4] + 1) * 10, TPB), TPB, 0, stream>>>((_Float16*)T1, (const float4*)curX, N[4], 80);
    conv(stream, T2, (const _Float16*)T1, nbr[4], p1Wsp, nullptr, nullptr, N[4], 80, 80, 27, N[4]);
    kscores<<<cdiv(N[4], TPB), TPB, 0, stream>>>(sc1, T2, ppn1_sw, N[4], 80);
    koutc<<<cdiv(N[4], TPB), TPB, 0, stream>>>(dout + (size_t)N[0] * 5, coords[4], sc1, N[4]);
    // ppn2 @ level 2
    kmulatt_h<<<cdiv((long)(N[2] + 1) * 6, TPB), TPB, 0, stream>>>((_Float16*)curX, (const float4*)fmap2, up1, sc1, N[2], 48);
    conv(stream, T1, (const _Float16*)curX, nbr[2], p2Wsp, nullptr, nullptr, N[2], 48, 48, 27, N[2]);
    kscores<<<cdiv(N[2], TPB), TPB, 0, stream>>>(sc2, T1, ppn2_sw, N[2], 48);
    koutc<<<cdiv(N[2], TPB), TPB, 0, stream>>>(dout + (size_t)(N[0] + N[4]) * 5, coords[2], sc2, N[2]);
    // ppn3 @ level 0
    kmulatt_h<<<cdiv((long)(N[0] + 1) * 2, TPB), TPB, 0, stream>>>((_Float16*)T2, (const float4*)fmap0, up2, sc2, N[0], 16);
    conv(stream, curX, (const _Float16*)T2, nbr[0], p3Wsp, nullptr, nullptr, N[0], 16, 16, 27, N[0]);
    kout0<<<cdiv(N[0], TPB), TPB, 0, stream>>>(dout, curX, ppn3_pw, ppn3_sw, N[0]);
}

// Round 16
// 1243.067 us; speedup vs baseline: 1.1337x; 1.1337x over previous
//
#include <hip/hip_runtime.h>
#include <cstdint>
#include <cstddef>

#define TPB 256

typedef _Float16 f16x8 __attribute__((ext_vector_type(8)));
typedef float f32x4 __attribute__((ext_vector_type(4)));

// raw barrier: LDS-visibility fence WITHOUT the vmcnt(0) drain __syncthreads emits.
// Global prefetch loads stay in flight across it (T3/T4). sched_barrier pins
// ds ops on the correct side (rule #18).
__device__ __forceinline__ void block_sync_lds() {
    asm volatile("s_waitcnt lgkmcnt(0)" ::: "memory");
    __builtin_amdgcn_sched_barrier(0);
    __builtin_amdgcn_s_barrier();
    __builtin_amdgcn_sched_barrier(0);
}

// ---------------- index-building kernels ----------------

static __global__ void kscatter(int* __restrict__ grid, const int* __restrict__ coords,
                                int N, int S) {
    int i = blockIdx.x * blockDim.x + threadIdx.x;
    if (i >= N) return;
    int x = coords[3 * i], y = coords[3 * i + 1], z = coords[3 * i + 2];
    grid[(x * S + y) * S + z] = i;
}

// invalid neighbors are remapped to zr (the zero-row index)
static __global__ void knbr27(int* __restrict__ nbr, const int* __restrict__ coords,
                              const int* __restrict__ grid, int N, int S, int zr) {
    int t = blockIdx.x * blockDim.x + threadIdx.x;
    if (t >= N * 27) return;
    int n = t / 27, k = t - 27 * n;
    int x = coords[3 * n]     + (k / 9) - 1;
    int y = coords[3 * n + 1] + ((k / 3) % 3) - 1;
    int z = coords[3 * n + 2] + (k % 3) - 1;
    int v = -1;
    if ((unsigned)x < (unsigned)S && (unsigned)y < (unsigned)S && (unsigned)z < (unsigned)S)
        v = grid[(x * S + y) * S + z];
    nbr[t] = (v < 0) ? zr : v;
}

static __global__ void kdown8(int* __restrict__ dn, const int* __restrict__ coords,
                              const int* __restrict__ grid, int M, int S_f, int zr) {
    int t = blockIdx.x * blockDim.x + threadIdx.x;
    if (t >= M * 8) return;
    int n = t >> 3, k = t & 7;
    int x = coords[3 * n] * 2     + ((k >> 2) & 1);
    int y = coords[3 * n + 1] * 2 + ((k >> 1) & 1);
    int z = coords[3 * n + 2] * 2 + (k & 1);
    int v = grid[(x * S_f + y) * S_f + z];
    dn[t] = (v < 0) ? zr : v;
}

static __global__ void kup(int* __restrict__ up, const int* __restrict__ cf,
                           const int* __restrict__ gc, int N, int Sc) {
    int n = blockIdx.x * blockDim.x + threadIdx.x;
    if (n >= N) return;
    int x = cf[3 * n] >> 2, y = cf[3 * n + 1] >> 2, z = cf[3 * n + 2] >> 2;
    up[n] = gc[(x * Sc + y) * Sc + z];       // parent always exists
}

// split weights: W[k][a][b] fp32 -> dst row per (k,b): [A hi halves][A lo halves]
// taps k >= KREAL (pad taps) are zero-filled.
static __global__ void ksplitw(_Float16* __restrict__ dst, const float* __restrict__ src,
                               int KREAL, int KPAD, int A, int B) {
    int t = blockIdx.x * blockDim.x + threadIdx.x;
    if (t >= KPAD * A * B) return;
    int a = t % A;
    int b = (t / A) % B;
    int k = t / (A * B);
    float v = (k < KREAL) ? src[((size_t)k * A + a) * B + b] : 0.0f;
    _Float16 hi = (_Float16)v;
    _Float16 lo = (_Float16)(v - (float)hi);
    size_t row = ((size_t)k * B + b) * (size_t)(2 * A);
    dst[row + a] = hi;
    dst[row + A + a] = lo;
}

// ---------------- BN stats + fused BN-ReLU-split pass ----------------
// stats slot layout: 16 copies x 160 doubles. kstats writes copy 0; fused conv
// epilogues spread over all 16; kbnrelu sums the 16 copies.

static __global__ void kstats(double* __restrict__ st, const float* __restrict__ x,
                              int N, int C) {
    extern __shared__ double sh[];          // 2 * 4*C doubles
    int tid = threadIdx.x;
    int c = tid % C, rl = tid / C;
    double s = 0.0, q = 0.0;
    int base = blockIdx.x * 256 + rl * 64;
    for (int it = 0; it < 64; it++) {
        int r = base + it;
        if (r < N) {
            double v = (double)x[(size_t)r * C + c];
            s += v;
            q = fma(v, v, q);
        }
    }
    double* ss = sh;
    double* sq = sh + 4 * C;
    ss[tid] = s; sq[tid] = q;
    __syncthreads();
    if (tid < C) {
        double S = ss[tid] + ss[tid + C] + ss[tid + 2 * C] + ss[tid + 3 * C];
        double Q = sq[tid] + sq[tid + C] + sq[tid + 2 * C] + sq[tid + 3 * C];
        atomicAdd(&st[tid], S);
        atomicAdd(&st[80 + tid], Q);
    }
}

// y has N+1 rows; row N is the zero row. Row layout: [C hi f16][C lo f16].
static __global__ void kbnrelu_h(_Float16* __restrict__ y, const float4* __restrict__ x,
                                 const double* __restrict__ st, const float* __restrict__ g,
                                 const float* __restrict__ b, int N, int C) {
    __shared__ float sc[80], bh[80];
    int tid = threadIdx.x;
    if (tid < C) {
        double invN = 1.0 / (double)N;
        double S = 0.0, Q = 0.0;
#pragma unroll
        for (int c = 0; c < 16; c++) {
            S += st[c * 160 + tid];
            Q += st[c * 160 + 80 + tid];
        }
        double mu = S * invN;
        double var = Q * invN - mu * mu;
        float s = g[tid] * rsqrtf((float)var + 1e-4f);
        sc[tid] = s;
        bh[tid] = b[tid] - (float)mu * s;
    }
    __syncthreads();
    int C8 = C >> 3;
    int chunks = (N + 1) * C8;
    int t = blockIdx.x * blockDim.x + tid;
    if (t >= chunks) return;
    int n = t / C8, cc = t - n * C8;
    f16x8 hi = {}, lo = {};
    if (n < N) {
        float4 q0 = x[n * (C >> 2) + cc * 2];
        float4 q1 = x[n * (C >> 2) + cc * 2 + 1];
        float v[8] = {q0.x, q0.y, q0.z, q0.w, q1.x, q1.y, q1.z, q1.w};
#pragma unroll
        for (int j = 0; j < 8; j++) {
            float r = fmaxf(fmaf(v[j], sc[cc * 8 + j], bh[cc * 8 + j]), 0.0f);
            _Float16 h = (_Float16)r;
            hi[j] = h;
            lo[j] = (_Float16)(r - (float)h);
        }
    }
    *(f16x8*)&y[(size_t)n * 2 * C + cc * 8] = hi;
    *(f16x8*)&y[(size_t)n * 2 * C + C + cc * 8] = lo;
}

// fp32 -> split f16 (for ppn1 input); N+1 rows, last zeroed
static __global__ void kcvt_h(_Float16* __restrict__ y, const float4* __restrict__ x,
                              int N, int C) {
    int C8 = C >> 3;
    int t = blockIdx.x * blockDim.x + threadIdx.x;
    if (t >= (N + 1) * C8) return;
    int n = t / C8, cc = t - n * C8;
    f16x8 hi = {}, lo = {};
    if (n < N) {
        float4 q0 = x[n * (C >> 2) + cc * 2];
        float4 q1 = x[n * (C >> 2) + cc * 2 + 1];
        float v[8] = {q0.x, q0.y, q0.z, q0.w, q1.x, q1.y, q1.z, q1.w};
#pragma unroll
        for (int j = 0; j < 8; j++) {
            _Float16 h = (_Float16)v[j];
            hi[j] = h;
            lo[j] = (_Float16)(v[j] - (float)h);
        }
    }
    *(f16x8*)&y[(size_t)n * 2 * C + cc * 8] = hi;
    *(f16x8*)&y[(size_t)n * 2 * C + C + cc * 8] = lo;
}

// attention multiply + split; N+1 rows, last zeroed
static __global__ void kmulatt_h(_Float16* __restrict__ y, const float4* __restrict__ fmap,
                                 const int* __restrict__ up, const float* __restrict__ sc,
                                 int N, int C) {
    int C8 = C >> 3;
    int t = blockIdx.x * blockDim.x + threadIdx.x;
    if (t >= (N + 1) * C8) return;
    int n = t / C8, cc = t - n * C8;
    f16x8 hi = {}, lo = {};
    if (n < N) {
        int p = up[n];
        float att = (sc[2 * p + 1] > sc[2 * p]) ? 1.0f : 0.0f;
        float4 q0 = fmap[n * (C >> 2) + cc * 2];
        float4 q1 = fmap[n * (C >> 2) + cc * 2 + 1];
        float v[8] = {q0.x, q0.y, q0.z, q0.w, q1.x, q1.y, q1.z, q1.w};
#pragma unroll
        for (int j = 0; j < 8; j++) {
            float r = v[j] * att;
            _Float16 h = (_Float16)r;
            hi[j] = h;
            lo[j] = (_Float16)(r - (float)h);
        }
    }
    *(f16x8*)&y[(size_t)n * 2 * C + cc * 8] = hi;
    *(f16x8*)&y[(size_t)n * 2 * C + C + cc * 8] = lo;
}

// ---------------- split-f16 MFMA sparse conv: occupancy-first ----------------
// out[n,b] (+= res) = sum_k sum_a feat[nbr[n,k],a] * W[k,a,b], computed as
// hi*hi + lo*hi + hi*lo with mfma_f32_16x16x32_f16 (fp32 acc).
// Session-best structure (r8, 1246us): TR=64/MT=1 -> 992-1560 blocks (~4
// blocks/CU, ~15 waves/CU) so OTHER BLOCKS hide the ~700cy scattered gather.
// A-operand: single-set regs (6 loads, 24 VGPR -> no serialization pressure),
// loaded immediately AFTER the MFMA that frees them (WAR-legal): latency spans
// 2 barriers + W-store + next W-LDS-reads + cross-block overlap.
// B-operand (weights): single-buffered swizzled LDS (2-way max),
// two raw barriers/iter (lgkmcnt(0)+s_barrier, NO vmcnt drain in loop).
// Fused BN-stats epilogue (stp!=nullptr, KG==1): block LDS-reduce -> 96 f64
// atomics into 16 spread copies. Bijective XCD swizzle (m204) on blockIdx.x.

template <int A, int B, int TAPS, int TPI, int TR, int MT, int KG, bool ADD>
__launch_bounds__(256, 2)
static __global__ void kconvmf(float* __restrict__ out, const _Float16* __restrict__ feat,
                               const int* __restrict__ nbr, const _Float16* __restrict__ Wsp,
                               const float* __restrict__ res, double* __restrict__ stp,
                               int N, int zr) {
    constexpr int NT_W = B / 16;                    // all waves cover all cols
    static_assert(TR == 4 * MT * 16, "tile/wave mismatch");
    constexpr int KPT = (TPI == 1) ? ((A + 31) & ~31)
                      : (TPI == 2) ? ((A + 15) & ~15)
                                   : ((A + 7) & ~7);
    constexpr int KT = TPI * KPT;
    static_assert(KT % 32 == 0, "KT must be multiple of 32");
    constexpr int KSTEPS = KT / 32;
    constexpr int KTCH = KT / 8;                    // logical 16B chunks per row
    constexpr int PKT = (KTCH == 12) ? 16 : KTCH;   // physical chunks (stride)
    static_assert(PKT == 8 || PKT == 16, "bad PKT");
    constexpr int RH = PKT * 8;                     // halves per weight row
    constexpr int QQ = KPT / 8;
    constexpr int AQ = A / 8;
    constexpr int A2 = 2 * A;
    constexpr int ITERS = (TAPS + TPI - 1) / TPI;
    constexpr int IPG = (ITERS + KG - 1) / KG;
    constexpr int WROWS = 2 * B;                    // hi rows then lo rows
    constexpr int WSBH = WROWS * RH;                // halves in W buffer
    constexpr int WTOT = WROWS * KTCH;              // logical chunk tasks
    constexpr int WPT = (WTOT + 255) / 256;

    __shared__ __attribute__((aligned(16))) _Float16 wsb[WSBH];
    __shared__ double sred[(KG == 1) ? 4 * 2 * B : 1];

    const int tid = threadIdx.x;

    // bijective XCD swizzle (m204)
    int bx;
    {
        int nwg = gridDim.x, bid = blockIdx.x;
        int q = nwg >> 3, r = nwg & 7, xcd = bid & 7, ix = bid >> 3;
        bx = (xcd < r) ? xcd * (q + 1) + ix : r * (q + 1) + (xcd - r) * q + ix;
    }
    const int row0 = bx * TR;
    const int it0 = (KG > 1) ? blockIdx.y * IPG : 0;
    const int it1 = (KG > 1) ? ((it0 + IPG < ITERS) ? it0 + IPG : ITERS) : ITERS;

    const int lane = tid & 63, wid = tid >> 6;
    const int lrow = lane & 15, lgrp = lane >> 4;
    const int mb = wid * MT * 16;

    // ---- hoisted per-thread weight-staging map ----
    int w_lds[WPT], w_off[WPT];
    bool w_ok[WPT], w_real[WPT];
#pragma unroll
    for (int i = 0; i < WPT; i++) {
        int task = tid + i * 256;
        bool ok = (WTOT % 256 == 0) || (task < WTOT);
        int tc = ok ? task : 0;
        int q = tc % KTCH;
        int row = tc / KTCH;
        int bcol = row % B, pp = row / B;
        int t = q / QQ, qq = q - t * QQ;
        w_lds[i] = row * RH + (q ^ (row & (PKT - 1))) * 8;
        w_off[i] = (t * B + bcol) * A2 + pp * A + qq * 8;
        w_ok[i] = ok;
        w_real[i] = ok && (qq < AQ);
    }
    int rowm[MT];
#pragma unroll
    for (int mt = 0; mt < MT; mt++) rowm[mt] = row0 + mb + mt * 16 + lrow;

    f32x4 acc[MT][NT_W];
#pragma unroll
    for (int mt = 0; mt < MT; mt++)
#pragma unroll
        for (int nt = 0; nt < NT_W; nt++)
            acc[mt][nt] = (f32x4){0.f, 0.f, 0.f, 0.f};

    int nidA[MT][TPI], nidB[MT][TPI];
    f16x8 fa[MT][KSTEPS][2];                 // single-set A fragments
    f16x8 wg[WPT];

    auto loadnbr = [&](auto& nd, int it) {
        int tb = it * TPI;
#pragma unroll
        for (int mt = 0; mt < MT; mt++)
#pragma unroll
            for (int t = 0; t < TPI; t++)
                nd[mt][t] = (rowm[mt] < N && tb + t < TAPS)
                          ? nbr[(size_t)rowm[mt] * TAPS + tb + t] : zr;
    };
    auto loadA = [&](const auto& nd) {
#pragma unroll
        for (int mt = 0; mt < MT; mt++)
#pragma unroll
            for (int ks = 0; ks < KSTEPS; ks++) {
                int qc = ks * 4 + lgrp;
                int t = qc / QQ;
                int cq = qc - t * QQ;
                int id;
                if constexpr (TPI == 1) id = nd[mt][0];
                else if constexpr (TPI == 2) id = (t == 0) ? nd[mt][0] : nd[mt][1];
                else {
                    int lo2 = (t == 0) ? nd[mt][0] : nd[mt][1];
                    int hi2 = (t == 2) ? nd[mt][2] : nd[mt][3];
                    id = (t < 2) ? lo2 : hi2;
                }
                const _Float16* p = feat + (size_t)id * A2 + cq * 8;
                if constexpr (QQ > AQ) {
                    bool okc = (cq < AQ);
                    fa[mt][ks][0] = okc ? *(const f16x8*)p : (f16x8){};
                    fa[mt][ks][1] = okc ? *(const f16x8*)(p + A) : (f16x8){};
                } else {
                    fa[mt][ks][0] = *(const f16x8*)p;
                    fa[mt][ks][1] = *(const f16x8*)(p + A);
                }
            }
    };
    auto loadW = [&](int it) {
        size_t base = (size_t)it * TPI * B * A2;
#pragma unroll
        for (int i = 0; i < WPT; i++)
            wg[i] = w_real[i] ? *(const f16x8*)&Wsp[base + w_off[i]] : (f16x8){};
    };
    auto storeW = [&]() {
#pragma unroll
        for (int i = 0; i < WPT; i++)
            if (w_ok[i]) *(f16x8*)&wsb[w_lds[i]] = wg[i];
    };
    auto domfma = [&]() {
#pragma unroll
        for (int ks = 0; ks < KSTEPS; ++ks) {
            const int qc = ks * 4 + lgrp;
            f16x8 bh[NT_W], bl[NT_W];
#pragma unroll
            for (int nt = 0; nt < NT_W; ++nt) {
                int rH = nt * 16 + lrow;
                bh[nt] = *(const f16x8*)&wsb[rH * RH + (qc ^ (rH & (PKT - 1))) * 8];
                int rL = B + rH;
                bl[nt] = *(const f16x8*)&wsb[rL * RH + (qc ^ (rL & (PKT - 1))) * 8];
            }
#pragma unroll
            for (int mt = 0; mt < MT; ++mt)
#pragma unroll
                for (int nt = 0; nt < NT_W; ++nt) {
                    acc[mt][nt] = __builtin_amdgcn_mfma_f32_16x16x32_f16(fa[mt][ks][0], bh[nt], acc[mt][nt], 0, 0, 0);
                    acc[mt][nt] = __builtin_amdgcn_mfma_f32_16x16x32_f16(fa[mt][ks][1], bh[nt], acc[mt][nt], 0, 0, 0);
                    acc[mt][nt] = __builtin_amdgcn_mfma_f32_16x16x32_f16(fa[mt][ks][0], bl[nt], acc[mt][nt], 0, 0, 0);
                }
        }
    };

    // prologue: A(it0) + W(it0) staged; nbr(it0+1) + W(it0+1) prefetched
    loadnbr(nidA, it0);
    loadA(nidA);
    loadW(it0);
    storeW();                            // compiler-counted vmcnt wait on wg
    if (it0 + 1 < it1) loadnbr(nidB, it0 + 1);
    block_sync_lds();                    // W(it0) visible
    if (it0 + 1 < it1) loadW(it0 + 1);

    // body(it): MFMA(it) | loadA(it+1) (regs freed by MFMA) | nbr(it+2) |
    //           barrier | storeW(it+1) | loadW(it+2) | barrier.
    // Global loads stay in flight across both raw barriers.
    auto body = [&](auto& ncur, const auto& nnx, int it) {
        const bool m1 = (it + 1 < it1), m2 = (it + 2 < it1);
        domfma();
        if (m1) loadA(nnx);              // A(it+1): hides under barriers + W phase
        if (m2) loadnbr(ncur, it + 2);
        if (m1) {
            block_sync_lds();            // all waves done reading wsb (W(it))
            storeW();                    // W(it+1) from wg
            if (m2) loadW(it + 2);       // refill wg; in flight across barrier
            block_sync_lds();            // W(it+1) visible
        }
    };
    for (int it = it0; it < it1; ) {
        body(nidA, nidB, it); ++it;
        if (it >= it1) break;
        body(nidB, nidA, it); ++it;
    }

    // epilogue: C layout col=lane&15, row=(lane>>4)*4+j; optional fused BN stats
    const bool dostats = (stp != nullptr);
    double ssum[NT_W], sqs[NT_W];
#pragma unroll
    for (int nt = 0; nt < NT_W; nt++) { ssum[nt] = 0.0; sqs[nt] = 0.0; }
#pragma unroll
    for (int mt = 0; mt < MT; ++mt) {
        int gr0 = row0 + mb + mt * 16 + lgrp * 4;
#pragma unroll
        for (int nt = 0; nt < NT_W; ++nt) {
            int gc = nt * 16 + lrow;
#pragma unroll
            for (int j = 0; j < 4; ++j) {
                int r = gr0 + j;
                if (r < N) {
                    size_t o = (size_t)r * B + gc;
                    if (KG > 1) {
                        atomicAdd(&out[o], acc[mt][nt][j]);
                    } else {
                        float v = acc[mt][nt][j];
                        if (ADD) v += res[o];
                        out[o] = v;
                        if (dostats) {
                            double dv = (double)v;
                            ssum[nt] += dv;
                            sqs[nt] = fma(dv, dv, sqs[nt]);
                        }
                    }
                }
            }
        }
    }
    if (KG == 1) {
        if (dostats) {
#pragma unroll
            for (int nt = 0; nt < NT_W; nt++) {
                ssum[nt] += __shfl_xor(ssum[nt], 16, 64);
                ssum[nt] += __shfl_xor(ssum[nt], 32, 64);
                sqs[nt] += __shfl_xor(sqs[nt], 16, 64);
                sqs[nt] += __shfl_xor(sqs[nt], 32, 64);
            }
            if (lgrp == 0) {
#pragma unroll
                for (int nt = 0; nt < NT_W; nt++) {
                    sred[(wid * 2 + 0) * B + nt * 16 + lrow] = ssum[nt];
                    sred[(wid * 2 + 1) * B + nt * 16 + lrow] = sqs[nt];
                }
            }
            __syncthreads();
            if (wid == 0) {
                double* sb = stp + (bx & 15) * 160;
                for (int c = lane; c < B; c += 64) {
                    double S = sred[c] + sred[2 * B + c] + sred[4 * B + c] + sred[6 * B + c];
                    double Q = sred[B + c] + sred[3 * B + c] + sred[5 * B + c] + sred[7 * B + c];
                    atomicAdd(&sb[c], S);
                    atomicAdd(&sb[80 + c], Q);
                }
            }
        }
    }
}

// input layer: A=1, B=16; vectorized over b-quads; fp32 (tiny)
static __global__ void kconv_in(float* __restrict__ out, const float* __restrict__ f,
                                const int* __restrict__ nbr, const float* __restrict__ W,
                                int N, int zr) {
    int t = blockIdx.x * blockDim.x + threadIdx.x;
    if (t >= N * 4) return;
    int n = t >> 2, bq = t & 3;
    float4 acc = make_float4(0.f, 0.f, 0.f, 0.f);
    const float4* W4 = (const float4*)W;
    for (int k = 0; k < 27; k++) {
        int id = nbr[n * 27 + k];
        if (id == zr) continue;
        float v = f[id];
        float4 w = W4[k * 4 + bq];
        acc.x = fmaf(v, w.x, acc.x);
        acc.y = fmaf(v, w.y, acc.y);
        acc.z = fmaf(v, w.z, acc.z);
        acc.w = fmaf(v, w.w, acc.w);
    }
    ((float4*)out)[n * 4 + bq] = acc;
}

// ---------------- heads / epilogue ----------------

static __global__ void kscores(float* __restrict__ sc, const float* __restrict__ x,
                               const float* __restrict__ w, int N, int C) {
    int n = blockIdx.x * blockDim.x + threadIdx.x;
    if (n >= N) return;
    float s0 = 0.0f, s1 = 0.0f;
    const float* xr = x + (size_t)n * C;
    for (int c = 0; c < C; c++) {
        float v = xr[c];
        s0 = fmaf(v, w[2 * c], s0);
        s1 = fmaf(v, w[2 * c + 1], s1);
    }
    sc[2 * n] = s0;
    sc[2 * n + 1] = s1;
}

static __global__ void kout0(float* __restrict__ out, const float* __restrict__ z,
                             const float* __restrict__ pw, const float* __restrict__ sw,
                             int N) {
    int n = blockIdx.x * blockDim.x + threadIdx.x;
    if (n >= N) return;
    float o0 = 0, o1 = 0, o2 = 0, o3 = 0, o4 = 0;
    const float* zr = z + (size_t)n * 16;
#pragma unroll
    for (int c = 0; c < 16; c++) {
        float v = zr[c];
        o0 = fmaf(v, pw[3 * c], o0);
        o1 = fmaf(v, pw[3 * c + 1], o1);
        o2 = fmaf(v, pw[3 * c + 2], o2);
        o3 = fmaf(v, sw[2 * c], o3);
        o4 = fmaf(v, sw[2 * c + 1], o4);
    }
    float* r = out + (size_t)n * 5;
    r[0] = o0; r[1] = o1; r[2] = o2; r[3] = o3; r[4] = o4;
}

static __global__ void koutc(float* __restrict__ out, const int* __restrict__ coords,
                             const float* __restrict__ sc, int N) {
    int n = blockIdx.x * blockDim.x + threadIdx.x;
    if (n >= N) return;
    float* r = out + (size_t)n * 5;
    r[0] = (float)coords[3 * n];
    r[1] = (float)coords[3 * n + 1];
    r[2] = (float)coords[3 * n + 2];
    r[3] = sc[2 * n];
    r[4] = sc[2 * n + 1];
}

// ---------------- host-side helpers ----------------

static inline int cdiv(long a, int b) { return (int)((a + b - 1) / b); }

static void conv(hipStream_t s, float* out, const _Float16* feat, const int* nbr,
                 const _Float16* Wsp, const float* res, double* stp,
                 int N, int A, int B, int TAPS, int zr) {
#define CASE(AA, BB, TT, TPI_, TR_, MT_, KG_)                                              \
    else if (A == AA && B == BB && TAPS == TT) {                                           \
        if (KG_ > 1 && !res) hipMemsetAsync(out, 0, (size_t)N * BB * 4, s);                \
        dim3 g(cdiv(N, TR_), KG_), blk(256);                                               \
        if (res) kconvmf<AA, BB, TT, TPI_, TR_, MT_, KG_, true><<<g, blk, 0, s>>>(out, feat, nbr, Wsp, res, stp, N, zr); \
        else     kconvmf<AA, BB, TT, TPI_, TR_, MT_, KG_, false><<<g, blk, 0, s>>>(out, feat, nbr, Wsp, nullptr, stp, N, zr); \
    }
    if (false) {}
    //    A   B  TAPS TPI  TR  MT KG    W-LDS / blocks
    CASE(16, 16, 27,  4,  64,  1, 1)   //  4KB, ~1560
    CASE(32, 32, 27,  2,  64,  1, 1)   //  8KB, ~1460
    CASE(48, 48, 27,  2,  64,  1, 1)   // 24KB, ~992
    CASE(64, 64, 27,  1,  64,  1, 4)   // 16KB, ~215x4
    CASE(80, 80, 27,  1,  64,  1, 9)   // 40KB, 27x9
    CASE(16, 32,  8,  4,  64,  1, 1)   //  8KB, ~1460
    CASE(32, 48,  8,  2,  64,  1, 1)   // 12KB, ~992
    CASE(48, 64,  8,  2,  64,  1, 2)   // 32KB, ~215x2
    CASE(64, 80,  8,  1,  64,  1, 4)   // 20KB, 27x4
#undef CASE
}

static void bnapply(hipStream_t s, _Float16* out, const float* x, double* st,
                    const float* g, const float* b, int N, int C, bool pre) {
    if (!pre)
        kstats<<<cdiv(N, 256), 4 * C, 8 * C * 2 * sizeof(double), s>>>(st, x, N, C);
    int chunks = (N + 1) * (C / 8);
    kbnrelu_h<<<cdiv(chunks, 256), 256, 0, s>>>(out, (const float4*)x, st, g, b, N, C);
}

extern "C" void kernel_launch(void* const* d_in, const int* in_sizes, int n_in,
                              void* d_out, int out_size, void* d_ws, size_t ws_size,
                              hipStream_t stream) {
    (void)n_in; (void)out_size; (void)ws_size;
    const int SL[5] = {192, 96, 48, 24, 12};
    const int C[5] = {16, 32, 48, 64, 80};
    int N[5];
    const int* coords[5];
    for (int l = 0; l < 5; l++) { N[l] = in_sizes[l] / 3; coords[l] = (const int*)d_in[l]; }
    const float* features = (const float*)d_in[5];
    const float* w_in = (const float*)d_in[6];
    const float *blk_w[4], *blk_g[4], *blk_b[4], *dn_g[4], *dn_b[4], *dn_w[4];
    for (int i = 0; i < 4; i++) {
        blk_w[i] = (const float*)d_in[7 + 6 * i];
        blk_g[i] = (const float*)d_in[8 + 6 * i];
        blk_b[i] = (const float*)d_in[9 + 6 * i];
        dn_g[i] = (const float*)d_in[10 + 6 * i];
        dn_b[i] = (const float*)d_in[11 + 6 * i];
        dn_w[i] = (const float*)d_in[12 + 6 * i];
    }
    const float* ppn1_w  = (const float*)d_in[31];
    const float* ppn1_sw = (const float*)d_in[32];
    const float* ppn2_w  = (const float*)d_in[33];
    const float* ppn2_sw = (const float*)d_in[34];
    const float* ppn3_w  = (const float*)d_in[35];
    const float* ppn3_pw = (const float*)d_in[36];
    const float* ppn3_sw = (const float*)d_in[37];
    float* dout = (float*)d_out;

    // ---- workspace layout ----
    char* ws = (char*)d_ws;
    size_t off = 0;
    auto alloc = [&](size_t bytes) -> char* {
        off = (off + 255) & ~(size_t)255;
        char* p = ws + off;
        off += bytes;
        return p;
    };
    int* nbr[5];
    for (int l = 0; l < 5; l++) nbr[l] = (int*)alloc((size_t)N[l] * 27 * 4);
    int* down8[4];
    for (int i = 0; i < 4; i++) down8[i] = (int*)alloc((size_t)N[i + 1] * 8 * 4);
    int* up1 = (int*)alloc((size_t)N[2] * 4);
    int* up2 = (int*)alloc((size_t)N[0] * 4);
    double* stats = (double*)alloc((size_t)26 * 2560 * sizeof(double));
    _Float16* blkWsp[4];
    _Float16* dnWsp[4];
    for (int i = 0; i < 4; i++) {
        blkWsp[i] = (_Float16*)alloc((size_t)4 * 28 * C[i] * 2 * C[i] * 2);
        dnWsp[i] = (_Float16*)alloc((size_t)8 * C[i + 1] * 2 * C[i] * 2);
    }
    _Float16* p1Wsp = (_Float16*)alloc((size_t)27 * 80 * 160 * 2);
    _Float16* p2Wsp = (_Float16*)alloc((size_t)28 * 48 * 96 * 2);
    _Float16* p3Wsp = (_Float16*)alloc((size_t)28 * 16 * 32 * 2);
    float* fmap0 = (float*)alloc((size_t)N[0] * 16 * 4);
    float* fmap2 = (float*)alloc((size_t)N[2] * 48 * 4);
    float* sc1 = (float*)alloc((size_t)N[4] * 2 * 4);
    float* sc2 = (float*)alloc((size_t)N[2] * 2 * 4);

    // transient region: grids (phase 1) alias the 3 rotating feature buffers (phase 2)
    size_t BIG = 0;
    for (int l = 0; l < 5; l++) {
        size_t s = (size_t)(N[l] + 1) * C[l] * 4;   // split rows = same bytes as fp32
        if (s > BIG) BIG = s;
    }
    BIG = (BIG + 255) & ~(size_t)255;
    off = (off + 255) & ~(size_t)255;
    size_t trans = off;
    int* grid[5];
    size_t gtot = 0;
    for (int l = 0; l < 5; l++) {
        grid[l] = (int*)(ws + trans + gtot);
        gtot += (size_t)SL[l] * SL[l] * SL[l] * 4;
    }
    float* B0 = (float*)(ws + trans);
    float* B1 = (float*)(ws + trans + BIG);
    float* B2 = (float*)(ws + trans + 2 * BIG);

    // ---- phase 1: index structures + weight splits + stats zero ----
    hipMemsetAsync(ws + trans, 0xFF, gtot, stream);  // all grids = -1
    hipMemsetAsync(stats, 0, (size_t)26 * 2560 * sizeof(double), stream);
    for (int l = 0; l < 5; l++)
        kscatter<<<cdiv(N[l], TPB), TPB, 0, stream>>>(grid[l], coords[l], N[l], SL[l]);
    for (int l = 0; l < 5; l++)
        knbr27<<<cdiv((long)N[l] * 27, TPB), TPB, 0, stream>>>(nbr[l], coords[l], grid[l], N[l], SL[l], N[l]);
    for (int i = 0; i < 4; i++)
        kdown8<<<cdiv((long)N[i + 1] * 8, TPB), TPB, 0, stream>>>(down8[i], coords[i + 1], grid[i], N[i + 1], SL[i], N[i]);
    kup<<<cdiv(N[2], TPB), TPB, 0, stream>>>(up1, coords[2], grid[4], N[2], 12);
    kup<<<cdiv(N[0], TPB), TPB, 0, stream>>>(up2, coords[0], grid[2], N[0], 48);
    for (int i = 0; i < 4; i++) {
        int Ci = C[i];
        for (int c = 0; c < 4; c++) {
            int n1 = 28 * Ci * Ci;
            ksplitw<<<cdiv(n1, TPB), TPB, 0, stream>>>(
                blkWsp[i] + (size_t)c * 28 * Ci * 2 * Ci,
                blk_w[i] + (size_t)c * 27 * Ci * Ci, 27, 28, Ci, Ci);
        }
        int n2 = 8 * Ci * C[i + 1];
        ksplitw<<<cdiv(n2, TPB), TPB, 0, stream>>>(dnWsp[i], dn_w[i], 8, 8, Ci, C[i + 1]);
    }
    ksplitw<<<cdiv(28 * 6400, TPB), TPB, 0, stream>>>(p1Wsp, ppn1_w, 27, 27, 80, 80);
    ksplitw<<<cdiv(28 * 2304, TPB), TPB, 0, stream>>>(p2Wsp, ppn2_w, 27, 28, 48, 48);
    ksplitw<<<cdiv(28 * 256, TPB), TPB, 0, stream>>>(p3Wsp, ppn3_w, 27, 28, 16, 16);

    // ---- phase 2: network (grids dead; B0/B1/B2 alias that memory) ----
    int slot = 0;
    auto stn = [&]() { return stats + 2560 * (slot++); };
    auto stpeek = [&]() { return stats + 2560 * slot; };

    float* curX = B0;
    kconv_in<<<cdiv((long)N[0] * 4, TPB), TPB, 0, stream>>>(curX, features, nbr[0], w_in, N[0], N[0]);
    hipMemcpyAsync(fmap0, curX, (size_t)N[0] * 16 * 4, hipMemcpyDeviceToDevice, stream);

    auto others = [&](float* cur, float*& t1, float*& t2) {
        if (cur == B0) { t1 = B1; t2 = B2; }
        else if (cur == B1) { t1 = B0; t2 = B2; }
        else { t1 = B0; t2 = B1; }
    };

    bool entryPre = false;   // stats for current curX already fused by its producer?
    for (int i = 0; i < 4; i++) {
        int Ni = N[i], Ci = C[i];
        float *T1, *T2;
        others(curX, T1, T2);
        size_t wsl = (size_t)28 * Ci * 2 * Ci;
        bool fuseL = (i < 3);                 // this level's 27-tap convs are KG==1
        for (int r = 0; r < 2; r++) {
            bnapply(stream, (_Float16*)T1, curX, stn(), blk_g[i] + (2 * r) * Ci,
                    blk_b[i] + (2 * r) * Ci, Ni, Ci, r == 0 ? entryPre : fuseL);
            conv(stream, T2, (const _Float16*)T1, nbr[i], blkWsp[i] + (2 * r) * wsl,
                 nullptr, fuseL ? stpeek() : nullptr, Ni, Ci, Ci, 27, Ni);
            bnapply(stream, (_Float16*)T1, T2, stn(), blk_g[i] + (2 * r + 1) * Ci,
                    blk_b[i] + (2 * r + 1) * Ci, Ni, Ci, fuseL);
            conv(stream, curX, (const _Float16*)T1, nbr[i], blkWsp[i] + (2 * r + 1) * wsl,
                 curX, fuseL ? stpeek() : nullptr, Ni, Ci, Ci, 27, Ni);
        }
        bnapply(stream, (_Float16*)T1, curX, stn(), dn_g[i], dn_b[i], Ni, Ci, fuseL);
        bool fuseD = (i < 2);                 // down0/down1 are KG==1
        conv(stream, T2, (const _Float16*)T1, down8[i], dnWsp[i], nullptr,
             fuseD ? stpeek() : nullptr, N[i + 1], Ci, C[i + 1], 8, Ni);
        entryPre = fuseD;
        if (i == 1)
            hipMemcpyAsync(fmap2, T2, (size_t)N[2] * 48 * 4, hipMemcpyDeviceToDevice, stream);
        curX = T2;
    }

    // ---- heads ----
    float *T1, *T2;
    others(curX, T1, T2);
    // ppn1 @ level 4: convert level-4 features to split-f16 (with zero row)
    kcvt_h<<<cdiv((N[4] + 1) * 10, TPB), TPB, 0, stream>>>((_Float16*)T1, (const float4*)curX, N[4], 80);
    conv(stream, T2, (const _Float16*)T1, nbr[4], p1Wsp, nullptr, nullptr, N[4], 80, 80, 27, N[4]);
    kscores<<<cdiv(N[4], TPB), TPB, 0, stream>>>(sc1, T2, ppn1_sw, N[4], 80);
    koutc<<<cdiv(N[4], TPB), TPB, 0, stream>>>(dout + (size_t)N[0] * 5, coords[4], sc1, N[4]);
    // ppn2 @ level 2
    kmulatt_h<<<cdiv((long)(N[2] + 1) * 6, TPB), TPB, 0, stream>>>((_Float16*)curX, (const float4*)fmap2, up1, sc1, N[2], 48);
    conv(stream, T1, (const _Float16*)curX, nbr[2], p2Wsp, nullptr, nullptr, N[2], 48, 48, 27, N[2]);
    kscores<<<cdiv(N[2], TPB), TPB, 0, stream>>>(sc2, T1, ppn2_sw, N[2], 48);
    koutc<<<cdiv(N[2], TPB), TPB, 0, stream>>>(dout + (size_t)(N[0] + N[4]) * 5, coords[2], sc2, N[2]);
    // ppn3 @ level 0
    kmulatt_h<<<cdiv((long)(N[0] + 1) * 2, TPB), TPB, 0, stream>>>((_Float16*)T2, (const float4*)fmap0, up2, sc2, N[0], 16);
    conv(stream, curX, (const _Float16*)T2, nbr[0], p3Wsp, nullptr, nullptr, N[0], 16, 16, 27, N[0]);
    kout0<<<cdiv(N[0], TPB), TPB, 0, stream>>>(dout, curX, ppn3_pw, ppn3_sw, N[0]);
}